// Round 3
// baseline (629.919 us; speedup 1.0000x reference)
//
#include <hip/hip_runtime.h>

#define BATCH 64
#define NIN 1024
#define IVL 64
#define ONUM 64
#define LVL 32
#define OLSZ 2048  // ONUM*LVL

typedef __attribute__((ext_vector_type(4))) float f32x4;
typedef __attribute__((ext_vector_type(8))) short short8;

static __device__ __forceinline__ unsigned short f2bf(float f) {
  unsigned u = __builtin_bit_cast(unsigned, f);
  u += 0x7fffu + ((u >> 16) & 1u);
  return (unsigned short)(u >> 16);
}
static __device__ __forceinline__ float bf2f_lo(unsigned x) {
  return __builtin_bit_cast(float, x << 16);
}
static __device__ __forceinline__ float bf2f_hi(unsigned x) {
  return __builtin_bit_cast(float, x & 0xffff0000u);
}

// K1: u_hat[b,n,o,l] = sum_i u[b,n,i]*W[n,o,l,i] + bias[n,o,l], stored bf16.
// Grid (n, quarter). Each wave owns 8 tiles of 16 cols. A=W frag, B=u frag
// (swapped operands) so D row = wcol (4 consecutive per lane -> 8B stores).
__global__ __launch_bounds__(256) void k_gemm(
    const float* __restrict__ u, const float* __restrict__ w,
    const float* __restrict__ bias, unsigned short* __restrict__ uhat) {
  const int n = blockIdx.x;
  const int quarter = blockIdx.y;
  __shared__ __align__(16) unsigned short a_lds[64 * 72];
  const int t = threadIdx.x;
  {
    const int b = t >> 2;
    const int i0 = (t & 3) * 16;
    const float* src = u + (size_t)b * (NIN * IVL) + (size_t)n * IVL + i0;
    unsigned short* dst = a_lds + b * 72 + i0;
#pragma unroll
    for (int q = 0; q < 4; ++q) {
      float4 v = *(const float4*)(src + q * 4);
      dst[q * 4 + 0] = f2bf(v.x);
      dst[q * 4 + 1] = f2bf(v.y);
      dst[q * 4 + 2] = f2bf(v.z);
      dst[q * 4 + 3] = f2bf(v.w);
    }
  }
  __syncthreads();
  const int lane = t & 63;
  const int wave = t >> 6;
  const int row16 = lane & 15;
  const int quad = lane >> 4;

  const int cbase = quarter * 512 + wave * 128;  // 8 tiles of 16 cols
  const float* wp =
      w + (size_t)n * (OLSZ * IVL) + (size_t)(cbase + row16) * IVL + quad * 8;
  const float* bb = bias + (size_t)n * OLSZ + cbase + quad * 4;
  unsigned short* ubase =
      uhat + ((size_t)row16 * NIN + n) * OLSZ + cbase + quad * 4;

  float4 cA0 = *(const float4*)(wp + 0);
  float4 cA1 = *(const float4*)(wp + 4);
  float4 cA2 = *(const float4*)(wp + 32);
  float4 cA3 = *(const float4*)(wp + 36);

#pragma unroll
  for (int tile = 0; tile < 8; ++tile) {
    float4 nA0, nA1, nA2, nA3;
    if (tile < 7) {
      const float* np_ = wp + (size_t)(tile + 1) * 1024;  // 16 cols * 64 i
      nA0 = *(const float4*)(np_ + 0);
      nA1 = *(const float4*)(np_ + 4);
      nA2 = *(const float4*)(np_ + 32);
      nA3 = *(const float4*)(np_ + 36);
    }
    // pack W tile -> bf16 A-fragments (k-halves)
    short8 wf0, wf1;
    wf0[0] = (short)f2bf(cA0.x); wf0[1] = (short)f2bf(cA0.y);
    wf0[2] = (short)f2bf(cA0.z); wf0[3] = (short)f2bf(cA0.w);
    wf0[4] = (short)f2bf(cA1.x); wf0[5] = (short)f2bf(cA1.y);
    wf0[6] = (short)f2bf(cA1.z); wf0[7] = (short)f2bf(cA1.w);
    wf1[0] = (short)f2bf(cA2.x); wf1[1] = (short)f2bf(cA2.y);
    wf1[2] = (short)f2bf(cA2.z); wf1[3] = (short)f2bf(cA2.w);
    wf1[4] = (short)f2bf(cA3.x); wf1[5] = (short)f2bf(cA3.y);
    wf1[6] = (short)f2bf(cA3.z); wf1[7] = (short)f2bf(cA3.w);

    float4 bv = *(const float4*)(bb + tile * 16);

    f32x4 acc[4];
#pragma unroll
    for (int bt = 0; bt < 4; ++bt) acc[bt] = (f32x4){0.f, 0.f, 0.f, 0.f};
#pragma unroll
    for (int bt = 0; bt < 4; ++bt) {
      const unsigned short* ul = a_lds + (bt * 16 + row16) * 72 + quad * 8;
      short8 uf0 = *(const short8*)(ul);
      short8 uf1 = *(const short8*)(ul + 32);
      acc[bt] =
          __builtin_amdgcn_mfma_f32_16x16x32_bf16(wf0, uf0, acc[bt], 0, 0, 0);
      acc[bt] =
          __builtin_amdgcn_mfma_f32_16x16x32_bf16(wf1, uf1, acc[bt], 0, 0, 0);
    }
#pragma unroll
    for (int bt = 0; bt < 4; ++bt) {
      unsigned h0 = f2bf(acc[bt][0] + bv.x);
      unsigned h1 = f2bf(acc[bt][1] + bv.y);
      unsigned h2 = f2bf(acc[bt][2] + bv.z);
      unsigned h3 = f2bf(acc[bt][3] + bv.w);
      uint2 pk = make_uint2(h0 | (h1 << 16), h2 | (h3 << 16));
      *(uint2*)(ubase + (size_t)bt * 16 * NIN * OLSZ + tile * 16) = pk;
    }
    cA0 = nA0; cA1 = nA1; cA2 = nA2; cA3 = nA3;
  }
}

// K2: s1[b,ol] = sum_n uhat[b,n,ol]. Dense coalesced.
__global__ __launch_bounds__(256) void k_sum_n(
    const unsigned short* __restrict__ uhat, float* __restrict__ s1) {
  const int b = blockIdx.x >> 5;
  const int chunk = blockIdx.x & 31;
  const int t = threadIdx.x;
  const unsigned short* base =
      uhat + ((size_t)b * NIN + (size_t)chunk * 32) * OLSZ + t * 8;
  float acc[8];
#pragma unroll
  for (int j = 0; j < 8; ++j) acc[j] = 0.f;
#pragma unroll 4
  for (int k = 0; k < 32; ++k) {
    uint4 p = *(const uint4*)(base + (size_t)k * OLSZ);
    unsigned xs[4] = {p.x, p.y, p.z, p.w};
#pragma unroll
    for (int h = 0; h < 4; ++h) {
      acc[2 * h] += bf2f_lo(xs[h]);
      acc[2 * h + 1] += bf2f_hi(xs[h]);
    }
  }
  float* s = s1 + (size_t)b * OLSZ + t * 8;
#pragma unroll
  for (int j = 0; j < 8; ++j) atomicAdd(s + j, acc[j]);
}

// K3/K4: one routing iteration, dense-coalesced + software pipelined.
// Element f = q*512 + lane*8 + j  <->  o = 16q + lane/4, l = (lane%4)*8 + j.
__global__ __launch_bounds__(256) void k_route(
    const unsigned short* __restrict__ uhat, const float* __restrict__ sv,
    float scale, float* __restrict__ b1, int add_b1,
    float* __restrict__ sout) {
  const int b = blockIdx.x >> 5;
  const int chunk = blockIdx.x & 31;
  const int t = threadIdx.x;
  const int lane = t & 63;
  const int wave = t >> 6;
  const int g = lane >> 2;
  __shared__ float red[4][OLSZ];  // 32 KB

  float v[4][8];
#pragma unroll
  for (int q = 0; q < 4; ++q) {
    const float* svp = sv + (size_t)b * OLSZ + q * 512 + lane * 8;
    float4 a0 = *(const float4*)svp;
    float4 a1 = *(const float4*)(svp + 4);
    v[q][0] = a0.x * scale; v[q][1] = a0.y * scale;
    v[q][2] = a0.z * scale; v[q][3] = a0.w * scale;
    v[q][4] = a1.x * scale; v[q][5] = a1.y * scale;
    v[q][6] = a1.z * scale; v[q][7] = a1.w * scale;
    float p = 0.f;
#pragma unroll
    for (int j = 0; j < 8; ++j) p = fmaf(v[q][j], v[q][j], p);
    p += __shfl_xor(p, 1);
    p += __shfl_xor(p, 2);
    float f = p / ((1.f + p) * (sqrtf(p) + 1e-5f));
#pragma unroll
    for (int j = 0; j < 8; ++j) v[q][j] *= f;
  }

  float racc[4][8];
#pragma unroll
  for (int q = 0; q < 4; ++q)
#pragma unroll
    for (int j = 0; j < 8; ++j) racc[q][j] = 0.f;

  const int n0 = chunk * 32 + wave * 8;
  const unsigned short* ub = uhat + ((size_t)b * NIN + n0) * OLSZ + lane * 8;

  uint4 pA[4], pB[4];
#pragma unroll
  for (int q = 0; q < 4; ++q) pA[q] = *(const uint4*)(ub + q * 512);

  auto process = [&](const uint4(&pk)[4], int k) {
    const int n = n0 + k;
    const size_t bbase = ((size_t)b * NIN + n) * ONUM + g;
    float b1v[4];
    if (add_b1) {
#pragma unroll
      for (int q = 0; q < 4; ++q) b1v[q] = b1[bbase + 16 * q];
    }
    float ud[4][8];
    float d[4];
#pragma unroll
    for (int q = 0; q < 4; ++q) {
      unsigned xs[4] = {pk[q].x, pk[q].y, pk[q].z, pk[q].w};
#pragma unroll
      for (int h = 0; h < 4; ++h) {
        ud[q][2 * h] = bf2f_lo(xs[h]);
        ud[q][2 * h + 1] = bf2f_hi(xs[h]);
      }
      float p = 0.f;
#pragma unroll
      for (int j = 0; j < 8; ++j) p = fmaf(ud[q][j], v[q][j], p);
      p += __shfl_xor(p, 1);
      p += __shfl_xor(p, 2);
      d[q] = p;
    }
    float bno[4];
    if (add_b1) {
#pragma unroll
      for (int q = 0; q < 4; ++q) bno[q] = d[q] + b1v[q];
    } else {
#pragma unroll
      for (int q = 0; q < 4; ++q) bno[q] = d[q];
      if ((lane & 3) == 0) {
#pragma unroll
        for (int q = 0; q < 4; ++q) b1[bbase + 16 * q] = d[q];
      }
    }
    float m = fmaxf(fmaxf(bno[0], bno[1]), fmaxf(bno[2], bno[3]));
#pragma unroll
    for (int dl = 4; dl < 64; dl <<= 1) m = fmaxf(m, __shfl_xor(m, dl));
    float e0 = __expf(bno[0] - m);
    float e1 = __expf(bno[1] - m);
    float e2 = __expf(bno[2] - m);
    float e3 = __expf(bno[3] - m);
    float ls = (e0 + e1) + (e2 + e3);
#pragma unroll
    for (int dl = 4; dl < 64; dl <<= 1) ls += __shfl_xor(ls, dl);
    float inv = 1.0f / ls;
    float c[4] = {e0 * inv, e1 * inv, e2 * inv, e3 * inv};
#pragma unroll
    for (int q = 0; q < 4; ++q) {
#pragma unroll
      for (int j = 0; j < 8; ++j)
        racc[q][j] = fmaf(c[q], ud[q][j], racc[q][j]);
    }
  };

#pragma unroll
  for (int kk = 0; kk < 4; ++kk) {
    {
#pragma unroll
      for (int q = 0; q < 4; ++q)
        pB[q] = *(const uint4*)(ub + (size_t)(2 * kk + 1) * OLSZ + q * 512);
    }
    process(pA, 2 * kk);
    if (2 * kk + 2 < 8) {
#pragma unroll
      for (int q = 0; q < 4; ++q)
        pA[q] = *(const uint4*)(ub + (size_t)(2 * kk + 2) * OLSZ + q * 512);
    }
    process(pB, 2 * kk + 1);
  }

#pragma unroll
  for (int q = 0; q < 4; ++q) {
    float* dst = &red[wave][q * 512 + lane * 8];
    *(float4*)(dst) =
        make_float4(racc[q][0], racc[q][1], racc[q][2], racc[q][3]);
    *(float4*)(dst + 4) =
        make_float4(racc[q][4], racc[q][5], racc[q][6], racc[q][7]);
  }
  __syncthreads();
  float* so = sout + (size_t)b * OLSZ;
#pragma unroll
  for (int j = 0; j < 8; ++j) {
    const int idx = t + 256 * j;
    float s = (red[0][idx] + red[1][idx]) + (red[2][idx] + red[3][idx]);
    atomicAdd(so + idx, s);
  }
}

// K5: out = squash(s3)
__global__ __launch_bounds__(256) void k_final(const float* __restrict__ s3,
                                               float* __restrict__ out) {
  const int b = blockIdx.x;
  const int t = threadIdx.x;
  __shared__ float norm2[64];
  if (t < 64) norm2[t] = 0.f;
  __syncthreads();
  float scv[8];
#pragma unroll
  for (int k = 0; k < 8; ++k) {
    int idx = t + k * 256;
    float sc = s3[b * OLSZ + idx];
    scv[k] = sc;
    atomicAdd(&norm2[idx >> 5], sc * sc);
  }
  __syncthreads();
#pragma unroll
  for (int k = 0; k < 8; ++k) {
    int idx = t + k * 256;
    int o = idx >> 5;
    float n2 = norm2[o];
    float f = n2 / ((1.f + n2) * (sqrtf(n2) + 1e-5f));
    out[b * OLSZ + idx] = scv[k] * f;
  }
}

extern "C" void kernel_launch(void* const* d_in, const int* in_sizes, int n_in,
                              void* d_out, int out_size, void* d_ws,
                              size_t ws_size, hipStream_t stream) {
  const float* u = (const float*)d_in[0];
  const float* w = (const float*)d_in[1];
  const float* bias = (const float*)d_in[2];
  float* out = (float*)d_out;

  char* ws = (char*)d_ws;
  unsigned short* uhat = (unsigned short*)ws;                 // 268435456 B
  float* b1 = (float*)(ws + (size_t)268435456);               // 16777216 B
  float* s1 = (float*)(ws + (size_t)268435456 + 16777216);    // 524288 B
  float* s2 = s1 + 131072;                                    // 524288 B
  float* s3 = s2 + 131072;                                    // 524288 B

  hipMemsetAsync(s1, 0, 3 * 131072 * sizeof(float), stream);

  k_gemm<<<dim3(1024, 4), dim3(256), 0, stream>>>(u, w, bias, uhat);
  k_sum_n<<<dim3(2048), dim3(256), 0, stream>>>(uhat, s1);
  k_route<<<dim3(2048), dim3(256), 0, stream>>>(uhat, s1, 1.0f / 64.0f, b1, 0, s2);
  k_route<<<dim3(2048), dim3(256), 0, stream>>>(uhat, s2, 1.0f, b1, 1, s3);
  k_final<<<dim3(64), dim3(256), 0, stream>>>(s3, out);
}

// Round 4
// 571.848 us; speedup vs baseline: 1.1016x; 1.1016x over previous
//
#include <hip/hip_runtime.h>

#define BATCH 64
#define NIN 1024
#define IVL 64
#define ONUM 64
#define LVL 32
#define OLSZ 2048  // ONUM*LVL

typedef __attribute__((ext_vector_type(4))) float f32x4;
typedef __attribute__((ext_vector_type(8))) short short8;

static __device__ __forceinline__ unsigned short f2bf(float f) {
  unsigned u = __builtin_bit_cast(unsigned, f);
  u += 0x7fffu + ((u >> 16) & 1u);
  return (unsigned short)(u >> 16);
}
static __device__ __forceinline__ float bf2f_lo(unsigned x) {
  return __builtin_bit_cast(float, x << 16);
}
static __device__ __forceinline__ float bf2f_hi(unsigned x) {
  return __builtin_bit_cast(float, x & 0xffff0000u);
}

// K1: u_hat[b,n,o,l] = sum_i u[b,n,i]*W[n,o,l,i] + bias[n,o,l], stored bf16.
// Grid (n, eighth). Wave owns 4 tiles of 16 cols. ALL W/bias loads issue as
// one burst pinned by sched_barrier(0) -> 320 B/lane in flight (MLP fix).
// A=W frag, B=u frag (swapped operands) so D row = wcol -> 8B stores.
__global__ __launch_bounds__(256) void k_gemm(
    const float* __restrict__ u, const float* __restrict__ w,
    const float* __restrict__ bias, unsigned short* __restrict__ uhat) {
  const int n = blockIdx.x;
  const int eighth = blockIdx.y;
  __shared__ __align__(16) unsigned short a_lds[64 * 72];
  const int t = threadIdx.x;
  const int lane = t & 63;
  const int wave = t >> 6;
  const int row16 = lane & 15;
  const int quad = lane >> 4;

  const int cbase = eighth * 256 + wave * 64;  // 4 tiles of 16 cols per wave
  const float* wp =
      w + (size_t)n * (OLSZ * IVL) + (size_t)(cbase + row16) * IVL + quad * 8;

  // ---- load burst: 16 x float4 of W + 4 x float4 bias, statically indexed
  float4 wv[16];
#pragma unroll
  for (int tile = 0; tile < 4; ++tile) {
    const float* p = wp + (size_t)tile * (16 * IVL);
    wv[tile * 4 + 0] = *(const float4*)(p + 0);
    wv[tile * 4 + 1] = *(const float4*)(p + 4);
    wv[tile * 4 + 2] = *(const float4*)(p + 32);
    wv[tile * 4 + 3] = *(const float4*)(p + 36);
  }
  float4 bv[4];
#pragma unroll
  for (int tile = 0; tile < 4; ++tile)
    bv[tile] = *(const float4*)(bias + (size_t)n * OLSZ + cbase + tile * 16 +
                                quad * 4);
  __builtin_amdgcn_sched_barrier(0);  // nothing moves above/below this point

  // ---- stage u[:, n, :] as bf16 into LDS (overlaps W latency)
  {
    const int b = t >> 2;
    const int i0 = (t & 3) * 16;
    const float* src = u + (size_t)b * (NIN * IVL) + (size_t)n * IVL + i0;
    unsigned short* dst = a_lds + b * 72 + i0;
#pragma unroll
    for (int q = 0; q < 4; ++q) {
      float4 v = *(const float4*)(src + q * 4);
      dst[q * 4 + 0] = f2bf(v.x);
      dst[q * 4 + 1] = f2bf(v.y);
      dst[q * 4 + 2] = f2bf(v.z);
      dst[q * 4 + 3] = f2bf(v.w);
    }
  }
  __syncthreads();

  // ---- u fragments, read once, kept in registers
  short8 uf[4][2];
#pragma unroll
  for (int bt = 0; bt < 4; ++bt) {
#pragma unroll
    for (int ks = 0; ks < 2; ++ks) {
      uf[bt][ks] =
          *(const short8*)(a_lds + (bt * 16 + row16) * 72 + ks * 32 + quad * 8);
    }
  }

  unsigned short* ubase =
      uhat + ((size_t)row16 * NIN + n) * OLSZ + cbase + quad * 4;

#pragma unroll
  for (int tile = 0; tile < 4; ++tile) {
    const float4 cA0 = wv[tile * 4 + 0];
    const float4 cA1 = wv[tile * 4 + 1];
    const float4 cA2 = wv[tile * 4 + 2];
    const float4 cA3 = wv[tile * 4 + 3];
    short8 wf0, wf1;
    wf0[0] = (short)f2bf(cA0.x); wf0[1] = (short)f2bf(cA0.y);
    wf0[2] = (short)f2bf(cA0.z); wf0[3] = (short)f2bf(cA0.w);
    wf0[4] = (short)f2bf(cA1.x); wf0[5] = (short)f2bf(cA1.y);
    wf0[6] = (short)f2bf(cA1.z); wf0[7] = (short)f2bf(cA1.w);
    wf1[0] = (short)f2bf(cA2.x); wf1[1] = (short)f2bf(cA2.y);
    wf1[2] = (short)f2bf(cA2.z); wf1[3] = (short)f2bf(cA2.w);
    wf1[4] = (short)f2bf(cA3.x); wf1[5] = (short)f2bf(cA3.y);
    wf1[6] = (short)f2bf(cA3.z); wf1[7] = (short)f2bf(cA3.w);

    f32x4 acc[4];
#pragma unroll
    for (int bt = 0; bt < 4; ++bt) acc[bt] = (f32x4){0.f, 0.f, 0.f, 0.f};
#pragma unroll
    for (int bt = 0; bt < 4; ++bt) {
      acc[bt] = __builtin_amdgcn_mfma_f32_16x16x32_bf16(wf0, uf[bt][0],
                                                        acc[bt], 0, 0, 0);
      acc[bt] = __builtin_amdgcn_mfma_f32_16x16x32_bf16(wf1, uf[bt][1],
                                                        acc[bt], 0, 0, 0);
    }
#pragma unroll
    for (int bt = 0; bt < 4; ++bt) {
      unsigned h0 = f2bf(acc[bt][0] + bv[tile].x);
      unsigned h1 = f2bf(acc[bt][1] + bv[tile].y);
      unsigned h2 = f2bf(acc[bt][2] + bv[tile].z);
      unsigned h3 = f2bf(acc[bt][3] + bv[tile].w);
      uint2 pk = make_uint2(h0 | (h1 << 16), h2 | (h3 << 16));
      *(uint2*)(ubase + (size_t)bt * 16 * NIN * OLSZ + tile * 16) = pk;
    }
  }
}

// K2: s1[b,ol] = sum_n uhat[b,n,ol]. Dense coalesced.
__global__ __launch_bounds__(256) void k_sum_n(
    const unsigned short* __restrict__ uhat, float* __restrict__ s1) {
  const int b = blockIdx.x >> 5;
  const int chunk = blockIdx.x & 31;
  const int t = threadIdx.x;
  const unsigned short* base =
      uhat + ((size_t)b * NIN + (size_t)chunk * 32) * OLSZ + t * 8;
  float acc[8];
#pragma unroll
  for (int j = 0; j < 8; ++j) acc[j] = 0.f;
#pragma unroll 4
  for (int k = 0; k < 32; ++k) {
    uint4 p = *(const uint4*)(base + (size_t)k * OLSZ);
    unsigned xs[4] = {p.x, p.y, p.z, p.w};
#pragma unroll
    for (int h = 0; h < 4; ++h) {
      acc[2 * h] += bf2f_lo(xs[h]);
      acc[2 * h + 1] += bf2f_hi(xs[h]);
    }
  }
  float* s = s1 + (size_t)b * OLSZ + t * 8;
#pragma unroll
  for (int j = 0; j < 8; ++j) atomicAdd(s + j, acc[j]);
}

// K3/K4: one routing iteration, dense-coalesced + software pipelined.
// Element f = q*512 + lane*8 + j  <->  o = 16q + lane/4, l = (lane%4)*8 + j.
__global__ __launch_bounds__(256) void k_route(
    const unsigned short* __restrict__ uhat, const float* __restrict__ sv,
    float scale, float* __restrict__ b1, int add_b1,
    float* __restrict__ sout) {
  const int b = blockIdx.x >> 5;
  const int chunk = blockIdx.x & 31;
  const int t = threadIdx.x;
  const int lane = t & 63;
  const int wave = t >> 6;
  const int g = lane >> 2;
  __shared__ float red[4][OLSZ];  // 32 KB

  float v[4][8];
#pragma unroll
  for (int q = 0; q < 4; ++q) {
    const float* svp = sv + (size_t)b * OLSZ + q * 512 + lane * 8;
    float4 a0 = *(const float4*)svp;
    float4 a1 = *(const float4*)(svp + 4);
    v[q][0] = a0.x * scale; v[q][1] = a0.y * scale;
    v[q][2] = a0.z * scale; v[q][3] = a0.w * scale;
    v[q][4] = a1.x * scale; v[q][5] = a1.y * scale;
    v[q][6] = a1.z * scale; v[q][7] = a1.w * scale;
    float p = 0.f;
#pragma unroll
    for (int j = 0; j < 8; ++j) p = fmaf(v[q][j], v[q][j], p);
    p += __shfl_xor(p, 1);
    p += __shfl_xor(p, 2);
    float f = p / ((1.f + p) * (sqrtf(p) + 1e-5f));
#pragma unroll
    for (int j = 0; j < 8; ++j) v[q][j] *= f;
  }

  float racc[4][8];
#pragma unroll
  for (int q = 0; q < 4; ++q)
#pragma unroll
    for (int j = 0; j < 8; ++j) racc[q][j] = 0.f;

  const int n0 = chunk * 32 + wave * 8;
  const unsigned short* ub = uhat + ((size_t)b * NIN + n0) * OLSZ + lane * 8;

  uint4 pA[4], pB[4];
#pragma unroll
  for (int q = 0; q < 4; ++q) pA[q] = *(const uint4*)(ub + q * 512);

  auto process = [&](const uint4(&pk)[4], int k) {
    const int n = n0 + k;
    const size_t bbase = ((size_t)b * NIN + n) * ONUM + g;
    float b1v[4];
    if (add_b1) {
#pragma unroll
      for (int q = 0; q < 4; ++q) b1v[q] = b1[bbase + 16 * q];
    }
    float ud[4][8];
    float d[4];
#pragma unroll
    for (int q = 0; q < 4; ++q) {
      unsigned xs[4] = {pk[q].x, pk[q].y, pk[q].z, pk[q].w};
#pragma unroll
      for (int h = 0; h < 4; ++h) {
        ud[q][2 * h] = bf2f_lo(xs[h]);
        ud[q][2 * h + 1] = bf2f_hi(xs[h]);
      }
      float p = 0.f;
#pragma unroll
      for (int j = 0; j < 8; ++j) p = fmaf(ud[q][j], v[q][j], p);
      p += __shfl_xor(p, 1);
      p += __shfl_xor(p, 2);
      d[q] = p;
    }
    float bno[4];
    if (add_b1) {
#pragma unroll
      for (int q = 0; q < 4; ++q) bno[q] = d[q] + b1v[q];
    } else {
#pragma unroll
      for (int q = 0; q < 4; ++q) bno[q] = d[q];
      if ((lane & 3) == 0) {
#pragma unroll
        for (int q = 0; q < 4; ++q) b1[bbase + 16 * q] = d[q];
      }
    }
    float m = fmaxf(fmaxf(bno[0], bno[1]), fmaxf(bno[2], bno[3]));
#pragma unroll
    for (int dl = 4; dl < 64; dl <<= 1) m = fmaxf(m, __shfl_xor(m, dl));
    float e0 = __expf(bno[0] - m);
    float e1 = __expf(bno[1] - m);
    float e2 = __expf(bno[2] - m);
    float e3 = __expf(bno[3] - m);
    float ls = (e0 + e1) + (e2 + e3);
#pragma unroll
    for (int dl = 4; dl < 64; dl <<= 1) ls += __shfl_xor(ls, dl);
    float inv = 1.0f / ls;
    float c[4] = {e0 * inv, e1 * inv, e2 * inv, e3 * inv};
#pragma unroll
    for (int q = 0; q < 4; ++q) {
#pragma unroll
      for (int j = 0; j < 8; ++j)
        racc[q][j] = fmaf(c[q], ud[q][j], racc[q][j]);
    }
  };

#pragma unroll
  for (int kk = 0; kk < 4; ++kk) {
    {
#pragma unroll
      for (int q = 0; q < 4; ++q)
        pB[q] = *(const uint4*)(ub + (size_t)(2 * kk + 1) * OLSZ + q * 512);
    }
    process(pA, 2 * kk);
    if (2 * kk + 2 < 8) {
#pragma unroll
      for (int q = 0; q < 4; ++q)
        pA[q] = *(const uint4*)(ub + (size_t)(2 * kk + 2) * OLSZ + q * 512);
    }
    process(pB, 2 * kk + 1);
  }

#pragma unroll
  for (int q = 0; q < 4; ++q) {
    float* dst = &red[wave][q * 512 + lane * 8];
    *(float4*)(dst) =
        make_float4(racc[q][0], racc[q][1], racc[q][2], racc[q][3]);
    *(float4*)(dst + 4) =
        make_float4(racc[q][4], racc[q][5], racc[q][6], racc[q][7]);
  }
  __syncthreads();
  float* so = sout + (size_t)b * OLSZ;
#pragma unroll
  for (int j = 0; j < 8; ++j) {
    const int idx = t + 256 * j;
    float s = (red[0][idx] + red[1][idx]) + (red[2][idx] + red[3][idx]);
    atomicAdd(so + idx, s);
  }
}

// K5: out = squash(s3)
__global__ __launch_bounds__(256) void k_final(const float* __restrict__ s3,
                                               float* __restrict__ out) {
  const int b = blockIdx.x;
  const int t = threadIdx.x;
  __shared__ float norm2[64];
  if (t < 64) norm2[t] = 0.f;
  __syncthreads();
  float scv[8];
#pragma unroll
  for (int k = 0; k < 8; ++k) {
    int idx = t + k * 256;
    float sc = s3[b * OLSZ + idx];
    scv[k] = sc;
    atomicAdd(&norm2[idx >> 5], sc * sc);
  }
  __syncthreads();
#pragma unroll
  for (int k = 0; k < 8; ++k) {
    int idx = t + k * 256;
    int o = idx >> 5;
    float n2 = norm2[o];
    float f = n2 / ((1.f + n2) * (sqrtf(n2) + 1e-5f));
    out[b * OLSZ + idx] = scv[k] * f;
  }
}

extern "C" void kernel_launch(void* const* d_in, const int* in_sizes, int n_in,
                              void* d_out, int out_size, void* d_ws,
                              size_t ws_size, hipStream_t stream) {
  const float* u = (const float*)d_in[0];
  const float* w = (const float*)d_in[1];
  const float* bias = (const float*)d_in[2];
  float* out = (float*)d_out;

  char* ws = (char*)d_ws;
  unsigned short* uhat = (unsigned short*)ws;                 // 268435456 B
  float* b1 = (float*)(ws + (size_t)268435456);               // 16777216 B
  float* s1 = (float*)(ws + (size_t)268435456 + 16777216);    // 524288 B
  float* s2 = s1 + 131072;                                    // 524288 B
  float* s3 = s2 + 131072;                                    // 524288 B

  hipMemsetAsync(s1, 0, 3 * 131072 * sizeof(float), stream);

  k_gemm<<<dim3(1024, 8), dim3(256), 0, stream>>>(u, w, bias, uhat);
  k_sum_n<<<dim3(2048), dim3(256), 0, stream>>>(uhat, s1);
  k_route<<<dim3(2048), dim3(256), 0, stream>>>(uhat, s1, 1.0f / 64.0f, b1, 0, s2);
  k_route<<<dim3(2048), dim3(256), 0, stream>>>(uhat, s2, 1.0f, b1, 1, s3);
  k_final<<<dim3(64), dim3(256), 0, stream>>>(s3, out);
}